// Round 5
// baseline (176.184 us; speedup 1.0000x reference)
//
#include <hip/hip_runtime.h>

// Exponential smoothing: s[-1]=v0; s[j] = w*s[j-1] + (1-w)*x[j]; out[j]=s[j]
// w = sigmoid(smoothing_weight[h]).
// Single-pass chained scan (reads values ONCE, writes out ONCE):
//   - block (b,c) loads its CL=32 time-steps into registers
//   - computes zero-seed chunk aggregate A, publishes to ws + release flag
//   - waits (parallel poll) for all c predecessor flags, acquire fence,
//     then deterministically accumulates carry = scan of A_0..A_{c-1} seeded v0
//   - rescans the register-held chunk with the carry, streams out.
// Ticket-based virtual block IDs guarantee progress (deps only on earlier
// tickets; aggregate publish is wait-free). Agent-scope atomics handle
// cross-XCD visibility. Full-walk carry => bit-deterministic output.

namespace {

constexpr int Bt  = 16;          // batch
constexpr int Tt  = 4096;        // time
constexpr int HD4 = 128;         // float4 channels per (b,t)  (h*d/4)
constexpr int CL  = 32;          // chunk length along t
constexpr int NC  = Tt / CL;     // 128 chunks per batch
constexpr int NBLK = NC * Bt;    // 2048 blocks

__device__ __forceinline__ float sigmoidf_(float x) {
    return 1.0f / (1.0f + expf(-x));
}

__global__ __launch_bounds__(HD4, 2) void ema_onepass(
    const float4* __restrict__ values4, const float* __restrict__ sw,
    const float4* __restrict__ v04, float4* __restrict__ out4,
    float4* __restrict__ agg4, int* __restrict__ flags,
    int* __restrict__ ticket) {

    __shared__ int s_vid;
    if (threadIdx.x == 0) s_vid = atomicAdd(ticket, 1);
    __syncthreads();
    const int vid = s_vid;
    const int b = vid & (Bt - 1);
    const int c = vid >> 4;          // chunk index; deps have strictly lower vid
    const int t4 = threadIdx.x;

    const float w   = sigmoidf_(sw[t4 >> 4]);
    const float omw = 1.0f - w;
    float Wc = w;
    #pragma unroll
    for (int i = 0; i < 5; ++i) Wc *= Wc;   // w^CL (CL=32)

    // Load chunk into registers: 32 x float4 per thread, coalesced.
    const size_t base = ((size_t)b * Tt + (size_t)c * CL) * HD4 + t4;
    const float4* p = values4 + base;
    float4 x[CL];
    #pragma unroll
    for (int u = 0; u < CL; ++u) x[u] = p[(size_t)u * HD4];

    // Zero-seed chunk aggregate.
    float4 A = make_float4(0.f, 0.f, 0.f, 0.f);
    #pragma unroll
    for (int u = 0; u < CL; ++u) {
        A.x = fmaf(w, A.x, omw * x[u].x);
        A.y = fmaf(w, A.y, omw * x[u].y);
        A.z = fmaf(w, A.z, omw * x[u].z);
        A.w = fmaf(w, A.w, omw * x[u].w);
    }

    // Publish aggregate; release flag after all block payload stores drained.
    agg4[((size_t)c * Bt + b) * HD4 + t4] = A;
    __syncthreads();   // emits vmcnt(0) drain before barrier
    if (threadIdx.x == 0)
        __hip_atomic_store(&flags[c * Bt + b], 1, __ATOMIC_RELEASE,
                           __HIP_MEMORY_SCOPE_AGENT);

    // Carry entering chunk c: s = v0; for k=0..c-1: s = Wc*s + A_k.
    float4 s = v04[t4];
    if (c > 0) {
        // Parallel flag wait: thread k watches predecessor k (c <= 127 < 128).
        for (;;) {
            int fl = 1;
            if (t4 < c)
                fl = __hip_atomic_load(&flags[t4 * Bt + b], __ATOMIC_RELAXED,
                                       __HIP_MEMORY_SCOPE_AGENT);
            if (__syncthreads_and(fl != 0)) break;
            __builtin_amdgcn_s_sleep(2);
        }
        __builtin_amdgcn_fence(__ATOMIC_ACQUIRE, "agent");

        const float4* a = agg4 + b * HD4 + t4;
        #pragma unroll 4
        for (int k = 0; k < c; ++k) {
            float4 Ak = a[(size_t)k * (Bt * HD4)];
            s.x = fmaf(Wc, s.x, Ak.x);
            s.y = fmaf(Wc, s.y, Ak.y);
            s.z = fmaf(Wc, s.z, Ak.z);
            s.w = fmaf(Wc, s.w, Ak.w);
        }
    }

    // Final rescan from registers with true seed; stream out.
    float4* q = out4 + base;
    #pragma unroll
    for (int u = 0; u < CL; ++u) {
        s.x = fmaf(w, s.x, omw * x[u].x);
        s.y = fmaf(w, s.y, omw * x[u].y);
        s.z = fmaf(w, s.z, omw * x[u].z);
        s.w = fmaf(w, s.w, omw * x[u].w);
        q[(size_t)u * HD4] = s;
    }
}

}  // namespace

extern "C" void kernel_launch(void* const* d_in, const int* in_sizes, int n_in,
                              void* d_out, int out_size, void* d_ws, size_t ws_size,
                              hipStream_t stream) {
    const float4* values4 = (const float4*)d_in[0];  // [16, 4096, 8, 64] f32
    const float*  sw      = (const float*)d_in[1];   // [8, 1]
    const float4* v04     = (const float4*)d_in[2];  // [1, 1, 8, 64]
    float4* out4 = (float4*)d_out;

    float4* agg4   = (float4*)d_ws;  // NBLK * HD4 float4 = 4 MiB
    int*    flags  = (int*)((char*)d_ws + (size_t)NBLK * HD4 * sizeof(float4));
    int*    ticket = flags + NBLK;

    hipMemsetAsync(flags, 0, (NBLK + 1) * sizeof(int), stream);
    ema_onepass<<<dim3(NBLK), dim3(HD4), 0, stream>>>(values4, sw, v04, out4,
                                                      agg4, flags, ticket);
}